// Round 6
// baseline (622.466 us; speedup 1.0000x reference)
//
#include <hip/hip_runtime.h>

typedef unsigned short u16;
typedef __attribute__((ext_vector_type(8))) short short8;   // 8 x bf16 (4 VGPRs)
typedef __attribute__((ext_vector_type(4))) float f32x4;    // MFMA C/D frag

#define DEVI __device__ __forceinline__

DEVI float u2f(u16 u) {
    unsigned int x = ((unsigned int)u) << 16;
    float f; __builtin_memcpy(&f, &x, 4); return f;
}
DEVI u16 f2u(float f) {  // RNE bf16 (finite values)
    unsigned int x; __builtin_memcpy(&x, &f, 4);
    x = (x + 0x7fffu + ((x >> 16) & 1u)) >> 16;
    return (u16)x;
}
// async global->LDS, 16B per lane; lds base must be wave-uniform (m104/m108)
DEVI void gld16(const u16* g, u16* ldsbase) {
    __builtin_amdgcn_global_load_lds(
        (const __attribute__((address_space(1))) unsigned int*)g,
        (__attribute__((address_space(3))) unsigned int*)ldsbase, 16, 0, 0);
}

// ---------------------------------------------------------------------------
// fp32 -> bf16 bulk convert: xb[i] = bf16(x[i]).  n multiple of 2048.
// grid n/2048, block 256; 8 floats/thread (float4 x2 load, short8 store).
__global__ __launch_bounds__(256) void cvt_bf16(
    const float* __restrict__ x, u16* __restrict__ xb, int n)
{
    int g = (blockIdx.x * 256 + threadIdx.x) * 8;
    float4 a = *(const float4*)&x[g];
    float4 b = *(const float4*)&x[g + 4];
    short8 v;
    v[0]=(short)f2u(a.x); v[1]=(short)f2u(a.y); v[2]=(short)f2u(a.z); v[3]=(short)f2u(a.w);
    v[4]=(short)f2u(b.x); v[5]=(short)f2u(b.y); v[6]=(short)f2u(b.z); v[7]=(short)f2u(b.w);
    *(short8*)&xb[g] = v;
}

// ---------------------------------------------------------------------------
// Weight transpose: WT[n][k] = bf16(W[k][n]).  W is [K][N] fp32.
// grid: (N/64, K/64), block 256.
__global__ __launch_bounds__(256) void transpose_k(
    const float* __restrict__ W, u16* __restrict__ WT, int K, int N)
{
    __shared__ u16 T[64 * 72];
    const int tid = threadIdx.x;
    const int k0 = blockIdx.y * 64, n0 = blockIdx.x * 64;
#pragma unroll
    for (int i = 0; i < 2; ++i) {
        int c = tid + i * 256;              // 0..511
        int row = c >> 3, n8 = (c & 7) * 8; // row: k-local
        const float* src = &W[(size_t)(k0 + row) * N + n0 + n8];
#pragma unroll
        for (int j = 0; j < 8; ++j)
            T[(n8 + j) * 72 + row] = f2u(src[j]);
    }
    __syncthreads();
#pragma unroll
    for (int i = 0; i < 2; ++i) {
        int c = tid + i * 256;
        int n = c >> 3, k8 = (c & 7) * 8;
        *(short8*)&WT[(size_t)(n0 + n) * K + k0 + k8] = *(const short8*)&T[n * 72 + k8];
    }
}

// ---------------------------------------------------------------------------
// GEMM: C[M][N] = A[M][K] @ WT[N][K]^T (+ optional fp32 residual).
// m97 structure: unpadded [128][32] LDS tiles, global_load_lds width=16 for
// BOTH bf16 operands.  C written fp32 if c_f32 else bf16.
// grid (N/128, M/128), block 256.
__global__ __launch_bounds__(256) void gemm_lds(
    const u16* __restrict__ A, int lda,
    const u16* __restrict__ WT,
    void* __restrict__ C, int ldc, const float* __restrict__ resid, int c_f32,
    int M, int N, int K)
{
    __shared__ u16 As[128 * 32];
    __shared__ u16 Bs[128 * 32];
    const int tid = threadIdx.x;
    const int lane = tid & 63, w = tid >> 6;
    const int wm = w >> 1, wn = w & 1;
    const int l15 = lane & 15, quad = lane >> 4;
    const int r4 = lane >> 2, c4 = (lane & 3) * 8;  // DMA: lane->row/col-8
    const int m0 = blockIdx.y * 128, n0 = blockIdx.x * 128;

    f32x4 acc[4][4] = {};
    for (int k0 = 0; k0 < K; k0 += 32) {
#pragma unroll
        for (int j = 0; j < 2; ++j) {
            int row = w * 32 + j * 16;
            gld16(&WT[(size_t)(n0 + row + r4) * K + k0 + c4], &Bs[row * 32]);
            gld16(&A [(size_t)(m0 + row + r4) * lda + k0 + c4], &As[row * 32]);
        }
        __syncthreads();
        short8 a[4], b[4];
#pragma unroll
        for (int mt = 0; mt < 4; ++mt)
            a[mt] = *(const short8*)&As[(wm * 64 + mt * 16 + l15) * 32 + quad * 8];
#pragma unroll
        for (int nt = 0; nt < 4; ++nt)
            b[nt] = *(const short8*)&Bs[(wn * 64 + nt * 16 + l15) * 32 + quad * 8];
#pragma unroll
        for (int mt = 0; mt < 4; ++mt)
#pragma unroll
            for (int nt = 0; nt < 4; ++nt)
                acc[mt][nt] = __builtin_amdgcn_mfma_f32_16x16x32_bf16(a[mt], b[nt], acc[mt][nt], 0, 0, 0);
        __syncthreads();
    }
#pragma unroll
    for (int mt = 0; mt < 4; ++mt) {
#pragma unroll
        for (int r = 0; r < 4; ++r) {
            int row = m0 + wm * 64 + mt * 16 + quad * 4 + r;
#pragma unroll
            for (int nt = 0; nt < 4; ++nt) {
                int col = n0 + wn * 64 + nt * 16 + l15;
                float v = acc[mt][nt][r];
                if (resid) v += resid[(size_t)row * ldc + col];
                if (c_f32) ((float*)C)[(size_t)row * ldc + col] = v;
                else       ((u16*)C)[(size_t)row * ldc + col] = f2u(v);
            }
        }
    }
}

// ---------------------------------------------------------------------------
// RMSNorm over dim_head=128, in-place on qkv buffer [4096][3072] (bf16).
// One wave per (token, head); heads 0..15 = q, 16..19 = k. grid 20480, block 256.
__global__ __launch_bounds__(256) void rmsnorm_qk(
    u16* __restrict__ qkv, const float* __restrict__ qg, const float* __restrict__ kg)
{
    const int tid = threadIdx.x, lane = tid & 63, w = tid >> 6;
    const int g = blockIdx.x * 4 + w;        // 0..81919
    const int token = g / 20, head = g % 20;
    const float* gamma; int off;
    if (head < 16) { off = head * 128; gamma = qg; }
    else           { off = 2048 + (head - 16) * 128; gamma = kg; }
    u16* p = qkv + (size_t)token * 3072 + off + lane * 2;
    float f0 = u2f(p[0]), f1 = u2f(p[1]);
    float ss = f0 * f0 + f1 * f1;
#pragma unroll
    for (int m = 1; m < 64; m <<= 1) ss += __shfl_xor(ss, m);
    float r = rsqrtf(ss * (1.0f / 128.0f) + 1e-8f);
    p[0] = f2u(f0 * r * gamma[lane * 2]);
    p[1] = f2u(f1 * r * gamma[lane * 2 + 1]);
}

// ---------------------------------------------------------------------------
// V transpose: vT[(b*4+kvh)*128 + d][s] = qkv[(b*2048+s)][2560 + kvh*128 + d]
// grid (32, 4, 2), block 256.  (bf16)
__global__ __launch_bounds__(256) void vtrans(
    const u16* __restrict__ qkv, u16* __restrict__ vT)
{
    __shared__ u16 T[128 * 72];
    const int tid = threadIdx.x;
    const int t0 = blockIdx.x * 64;
    const int kvh = blockIdx.y, b = blockIdx.z;
#pragma unroll
    for (int i = 0; i < 4; ++i) {
        int c = tid + i * 256;                // 0..1023
        int tl = c >> 4, d8 = (c & 15) * 8;
        short8 v = *(const short8*)&qkv[(size_t)(b * 2048 + t0 + tl) * 3072 + 2560 + kvh * 128 + d8];
#pragma unroll
        for (int j = 0; j < 8; ++j)
            T[(d8 + j) * 72 + tl] = (u16)v[j];
    }
    __syncthreads();
#pragma unroll
    for (int i = 0; i < 4; ++i) {
        int c = tid + i * 256;
        int d = c >> 3, t8 = (c & 7) * 8;
        *(short8*)&vT[((size_t)(b * 4 + kvh) * 128 + d) * 2048 + t0 + t8] =
            *(const short8*)&T[d * 72 + t8];
    }
}

// ---------------------------------------------------------------------------
// Flash attention, causal, GQA, PAIRED q-tiles (qt, 31-qt) => uniform 33
// kv-tiles/block, no CU-stacking imbalance.  LDS row strides padded to an
// ODD dword count (Qs/Ks 138 u16 = 69 dw, Vs/Ps 74 u16 = 37 dw) so b128
// fragment reads hit all 32 banks 2-way (free) instead of 8-way.
// grid (16, 16, 2), block 256.  LDS 55,552 B -> 2 blocks/CU.
#define QS 138
#define VS 74
__global__ __launch_bounds__(256) void attn(
    u16* __restrict__ qkv, const u16* __restrict__ vT)
{
    __shared__ u16 lds[27776];               // 55,552 B
    u16* const Ks  = lds;                    // [64][QS]   8832
    u16* const Vs  = lds + 8832;             // [128][VS]  9472
    u16* const Psb[2] = { lds + 18304, lds + 23040 };  // 2x [64][VS] 4736
    // Q staging overlays Vs+Ps (dead until first kv iteration):
    u16* const Qsb[2] = { lds + 8832, lds + 17664 };   // 2x [64][QS]

    const int tid = threadIdx.x, lane = tid & 63, w = tid >> 6;
    const int l15 = lane & 15, quad = lane >> 4;
    const int h = blockIdx.y, b = blockIdx.z;
    const int kvh = h >> 2;
    const int qts[2] = { (int)blockIdx.x, 31 - (int)blockIdx.x };
    const float scale = 0.08838834764831845f;

    // stage both Q tiles, pull fragments to registers
#pragma unroll
    for (int t = 0; t < 2; ++t)
#pragma unroll
        for (int i = 0; i < 4; ++i) {
            int c = tid + i * 256;
            int r = c >> 4, d8 = (c & 15) * 8;
            *(short8*)&Qsb[t][r * QS + d8] =
                *(const short8*)&qkv[(size_t)(b * 2048 + qts[t] * 64 + r) * 3072 + h * 128 + d8];
        }
    __syncthreads();
    short8 qf[2][4];
#pragma unroll
    for (int t = 0; t < 2; ++t)
#pragma unroll
        for (int ks = 0; ks < 4; ++ks)
            qf[t][ks] = *(const short8*)&Qsb[t][(w * 16 + l15) * QS + ks * 32 + quad * 8];
    __syncthreads();   // Q region about to be reused as Vs/Ps

    f32x4 o[2][8] = {};
    float mrow[2][4], lrow[2][4];
#pragma unroll
    for (int t = 0; t < 2; ++t)
#pragma unroll
        for (int r = 0; r < 4; ++r) { mrow[t][r] = -1e30f; lrow[t][r] = 0.f; }

    for (int kt = 0; kt <= qts[1]; ++kt) {
        const int kv0 = kt * 64;
#pragma unroll
        for (int i = 0; i < 4; ++i) {
            int c = tid + i * 256;
            int r = c >> 4, d8 = (c & 15) * 8;
            *(short8*)&Ks[r * QS + d8] =
                *(const short8*)&qkv[(size_t)(b * 2048 + kv0 + r) * 3072 + 2048 + kvh * 128 + d8];
        }
#pragma unroll
        for (int i = 0; i < 4; ++i) {
            int c = tid + i * 256;
            int d = c >> 3, t8 = (c & 7) * 8;
            *(short8*)&Vs[d * VS + t8] =
                *(const short8*)&vT[((size_t)(b * 4 + kvh) * 128 + d) * 2048 + kv0 + t8];
        }
        __syncthreads();

#pragma unroll
        for (int t = 0; t < 2; ++t) {
            if (kt > qts[t]) continue;       // tile done (wave-uniform branch)
            // S = Q K^T  (16 q-rows x 64 kv-cols)
            f32x4 s[4];
#pragma unroll
            for (int nt = 0; nt < 4; ++nt) {
                f32x4 a = {};
#pragma unroll
                for (int ks = 0; ks < 4; ++ks) {
                    short8 bk = *(const short8*)&Ks[(nt * 16 + l15) * QS + ks * 32 + quad * 8];
                    a = __builtin_amdgcn_mfma_f32_16x16x32_bf16(qf[t][ks], bk, a, 0, 0, 0);
                }
                s[nt] = a;
            }
            const bool diag = (kt == qts[t]);
#pragma unroll
            for (int nt = 0; nt < 4; ++nt) {
                int col = nt * 16 + l15;
#pragma unroll
                for (int r = 0; r < 4; ++r) {
                    float v = s[nt][r] * scale;
                    if (diag) {
                        int row = w * 16 + quad * 4 + r;
                        if (col > row) v = -1e30f;
                    }
                    s[nt][r] = v;
                }
            }
            // online softmax
            float alpha[4];
#pragma unroll
            for (int r = 0; r < 4; ++r) {
                float mx = s[0][r];
#pragma unroll
                for (int nt = 1; nt < 4; ++nt) mx = fmaxf(mx, s[nt][r]);
#pragma unroll
                for (int msk = 1; msk < 16; msk <<= 1) mx = fmaxf(mx, __shfl_xor(mx, msk));
                float mn = fmaxf(mrow[t][r], mx);
                alpha[r] = __expf(mrow[t][r] - mn);
                mrow[t][r] = mn;
            }
#pragma unroll
            for (int r = 0; r < 4; ++r) {
                float sum = 0.f;
#pragma unroll
                for (int nt = 0; nt < 4; ++nt) {
                    float p = __expf(s[nt][r] - mrow[t][r]);
                    s[nt][r] = p;
                    sum += p;
                }
#pragma unroll
                for (int msk = 1; msk < 16; msk <<= 1) sum += __shfl_xor(sum, msk);
                lrow[t][r] = lrow[t][r] * alpha[r] + sum;
            }
#pragma unroll
            for (int nt = 0; nt < 4; ++nt)
#pragma unroll
                for (int r = 0; r < 4; ++r)
                    Psb[t][(w * 16 + quad * 4 + r) * VS + nt * 16 + l15] = f2u(s[nt][r]);
#pragma unroll
            for (int nto = 0; nto < 8; ++nto)
#pragma unroll
                for (int r = 0; r < 4; ++r)
                    o[t][nto][r] *= alpha[r];
        }
        __syncthreads();

        // O += P @ V  (per active tile)
#pragma unroll
        for (int t = 0; t < 2; ++t) {
            if (kt > qts[t]) continue;
            short8 pa[2];
#pragma unroll
            for (int ks = 0; ks < 2; ++ks)
                pa[ks] = *(const short8*)&Psb[t][(w * 16 + l15) * VS + ks * 32 + quad * 8];
#pragma unroll
            for (int nto = 0; nto < 8; ++nto) {
#pragma unroll
                for (int ks = 0; ks < 2; ++ks) {
                    short8 bv = *(const short8*)&Vs[(nto * 16 + l15) * VS + ks * 32 + quad * 8];
                    o[t][nto] = __builtin_amdgcn_mfma_f32_16x16x32_bf16(pa[ks], bv, o[t][nto], 0, 0, 0);
                }
            }
        }
        __syncthreads();
    }
    // write O in-place over the Q slice (row stride 3072)
#pragma unroll
    for (int t = 0; t < 2; ++t)
#pragma unroll
        for (int r = 0; r < 4; ++r) {
            float inv = 1.0f / lrow[t][r];
            int row = qts[t] * 64 + w * 16 + quad * 4 + r;
#pragma unroll
            for (int nto = 0; nto < 8; ++nto)
                qkv[(size_t)(b * 2048 + row) * 3072 + h * 128 + nto * 16 + l15] =
                    f2u(o[t][nto][r] * inv);
        }
}

// ---------------------------------------------------------------------------
// Workspace layout (peak 46.1 MiB, proven):
//   [0,         8388608)  WoT   [2048][2048]   live until final GEMM
//   [8388608,  33554432)  QKV   [4096][3072]   q-slice becomes O in-place
//   [33554432, 37748736)  vT    [8][128][2048] written AFTER WTqkv is dead
//   [33554432, 46137344)  WTqkv [3072][2048]   dead after QKV GEMM
// xbf (bf16 copy of x, 16.8 MB) lives in d_out (dead until final GEMM).
extern "C" void kernel_launch(void* const* d_in, const int* in_sizes, int n_in,
                              void* d_out, int out_size, void* d_ws, size_t ws_size,
                              hipStream_t stream) {
    const float* x  = (const float*)d_in[0];   // [2,2048,2048] fp32
    const float* Wq = (const float*)d_in[1];   // [2048,2048]
    const float* Wk = (const float*)d_in[2];   // [2048,512]
    const float* Wv = (const float*)d_in[3];   // [2048,512]
    const float* Wo = (const float*)d_in[4];   // [2048,2048]
    const float* qg = (const float*)d_in[5];   // [128]
    const float* kg = (const float*)d_in[6];   // [128]

    char* ws = (char*)d_ws;
    u16* WoT   = (u16*)(ws);
    u16* QKV   = (u16*)(ws + 8388608);
    u16* vT    = (u16*)(ws + 33554432);
    u16* WTqkv = (u16*)(ws + 33554432);
    u16* xbf   = (u16*)d_out;                  // 16.8 MB of 33.5 MB; dead at GEMM2

    // 0. x -> bf16 (memory-bound, ~10 us)
    cvt_bf16<<<dim3(4096), 256, 0, stream>>>(x, xbf, 8388608);

    // 1. transpose weights into K-inner bf16 layout
    transpose_k<<<dim3(32, 32), 256, 0, stream>>>(Wo, WoT, 2048, 2048);
    transpose_k<<<dim3(32, 32), 256, 0, stream>>>(Wq, WTqkv, 2048, 2048);
    transpose_k<<<dim3(8, 32), 256, 0, stream>>>(Wk, WTqkv + (size_t)2048 * 2048, 2048, 512);
    transpose_k<<<dim3(8, 32), 256, 0, stream>>>(Wv, WTqkv + (size_t)2560 * 2048, 2048, 512);

    // 2. QKV projection: [4096][2048] @ -> [4096][3072]  (pure-DMA staging)
    gemm_lds<<<dim3(24, 32), 256, 0, stream>>>(xbf, 2048, WTqkv, QKV, 3072,
                                               nullptr, 0, 4096, 3072, 2048);

    // 3. RMSNorm on q,k heads; V transpose (WTqkv now dead; vT overlays it)
    rmsnorm_qk<<<dim3(20480), 256, 0, stream>>>(QKV, qg, kg);
    vtrans<<<dim3(32, 4, 2), 256, 0, stream>>>(QKV, vT);

    // 4. causal GQA flash attention (paired q-tiles), O in-place into QKV
    attn<<<dim3(16, 16, 2), 256, 0, stream>>>(QKV, vT);

    // 5. output projection + residual (A = O bf16 via DMA, C = d_out fp32)
    gemm_lds<<<dim3(16, 32), 256, 0, stream>>>(QKV, 3072, WoT, d_out, 2048,
                                               x, 1, 4096, 2048, 2048);
}

// Round 7
// 371.807 us; speedup vs baseline: 1.6742x; 1.6742x over previous
//
#include <hip/hip_runtime.h>

typedef unsigned short u16;
typedef __attribute__((ext_vector_type(8))) short short8;   // 8 x bf16 (4 VGPRs)
typedef __attribute__((ext_vector_type(4))) float f32x4;    // MFMA C/D frag

#define DEVI __device__ __forceinline__

DEVI float u2f(u16 u) {
    unsigned int x = ((unsigned int)u) << 16;
    float f; __builtin_memcpy(&f, &x, 4); return f;
}
DEVI u16 f2u(float f) {  // RNE bf16 (finite values)
    unsigned int x; __builtin_memcpy(&x, &f, 4);
    x = (x + 0x7fffu + ((x >> 16) & 1u)) >> 16;
    return (u16)x;
}
// async global->LDS, 16B per lane; lds base must be wave-uniform (m104/m108)
DEVI void gld16(const u16* g, u16* ldsbase) {
    __builtin_amdgcn_global_load_lds(
        (const __attribute__((address_space(1))) unsigned int*)g,
        (__attribute__((address_space(3))) unsigned int*)ldsbase, 16, 0, 0);
}

// ---------------------------------------------------------------------------
// fp32 -> bf16 bulk convert: xb[i] = bf16(x[i]).
// grid n/2048, block 256; 8 floats/thread.
__global__ __launch_bounds__(256) void cvt_bf16(
    const float* __restrict__ x, u16* __restrict__ xb, int n)
{
    int g = (blockIdx.x * 256 + threadIdx.x) * 8;
    float4 a = *(const float4*)&x[g];
    float4 b = *(const float4*)&x[g + 4];
    short8 v;
    v[0]=(short)f2u(a.x); v[1]=(short)f2u(a.y); v[2]=(short)f2u(a.z); v[3]=(short)f2u(a.w);
    v[4]=(short)f2u(b.x); v[5]=(short)f2u(b.y); v[6]=(short)f2u(b.z); v[7]=(short)f2u(b.w);
    *(short8*)&xb[g] = v;
}

// ---------------------------------------------------------------------------
// All four weight transposes in ONE launch: WT[n][k] = bf16(W[k][n]).
// Blocks 0..1023: Wo; 1024..2047: Wq; 2048..2303: Wk; 2304..2559: Wv.
// grid 2560, block 256.
__global__ __launch_bounds__(256) void transpose_all(
    const float* __restrict__ Wq, const float* __restrict__ Wk,
    const float* __restrict__ Wv, const float* __restrict__ Wo,
    u16* __restrict__ WTqkv, u16* __restrict__ WoT)
{
    __shared__ u16 T[64 * 72];
    int id = blockIdx.x;
    const float* W; u16* WT; int N, bx, by;
    if (id < 1024)      {            W = Wo; WT = WoT;   N = 2048; bx = id & 31; by = id >> 5; }
    else if (id < 2048) { id -= 1024; W = Wq; WT = WTqkv; N = 2048; bx = id & 31; by = id >> 5; }
    else if (id < 2304) { id -= 2048; W = Wk; WT = WTqkv + (size_t)2048 * 2048; N = 512; bx = id & 7; by = id >> 3; }
    else                { id -= 2304; W = Wv; WT = WTqkv + (size_t)2560 * 2048; N = 512; bx = id & 7; by = id >> 3; }
    const int K = 2048;
    const int tid = threadIdx.x;
    const int k0 = by * 64, n0 = bx * 64;
#pragma unroll
    for (int i = 0; i < 2; ++i) {
        int c = tid + i * 256;              // 0..511
        int row = c >> 3, n8 = (c & 7) * 8;
        const float* src = &W[(size_t)(k0 + row) * N + n0 + n8];
#pragma unroll
        for (int j = 0; j < 8; ++j)
            T[(n8 + j) * 72 + row] = f2u(src[j]);
    }
    __syncthreads();
#pragma unroll
    for (int i = 0; i < 2; ++i) {
        int c = tid + i * 256;
        int n = c >> 3, k8 = (c & 7) * 8;
        *(short8*)&WT[(size_t)(n0 + n) * K + k0 + k8] = *(const short8*)&T[n * 72 + k8];
    }
}

// ---------------------------------------------------------------------------
// GEMM: C[M][N] = A[M][K] @ WT[N][K]^T (+ optional fp32 residual).
// m97 structure: unpadded [128][32] LDS tiles, global_load_lds width=16.
// If fuse_norm: N-tiles with n0<2560 get per-head RMSNorm fused in the
// epilogue (each 128-col tile is exactly one head; gamma = qg for n0<2048,
// kg for 2048<=n0<2560; v-tiles untouched).
// C written fp32 if c_f32 else bf16.  grid (N/128, M/128), block 256.
__global__ __launch_bounds__(256) void gemm_lds(
    const u16* __restrict__ A, int lda,
    const u16* __restrict__ WT,
    void* __restrict__ C, int ldc, const float* __restrict__ resid, int c_f32,
    int M, int N, int K,
    const float* __restrict__ qg, const float* __restrict__ kg, int fuse_norm)
{
    __shared__ u16 As[128 * 32];
    __shared__ u16 Bs[128 * 32];
    const int tid = threadIdx.x;
    const int lane = tid & 63, w = tid >> 6;
    const int wm = w >> 1, wn = w & 1;
    const int l15 = lane & 15, quad = lane >> 4;
    const int r4 = lane >> 2, c4 = (lane & 3) * 8;  // DMA: lane->row/col-8
    const int m0 = blockIdx.y * 128, n0 = blockIdx.x * 128;

    f32x4 acc[4][4] = {};
    for (int k0 = 0; k0 < K; k0 += 32) {
#pragma unroll
        for (int j = 0; j < 2; ++j) {
            int row = w * 32 + j * 16;
            gld16(&WT[(size_t)(n0 + row + r4) * K + k0 + c4], &Bs[row * 32]);
            gld16(&A [(size_t)(m0 + row + r4) * lda + k0 + c4], &As[row * 32]);
        }
        __syncthreads();
        short8 a[4], b[4];
#pragma unroll
        for (int mt = 0; mt < 4; ++mt)
            a[mt] = *(const short8*)&As[(wm * 64 + mt * 16 + l15) * 32 + quad * 8];
#pragma unroll
        for (int nt = 0; nt < 4; ++nt)
            b[nt] = *(const short8*)&Bs[(wn * 64 + nt * 16 + l15) * 32 + quad * 8];
#pragma unroll
        for (int mt = 0; mt < 4; ++mt)
#pragma unroll
            for (int nt = 0; nt < 4; ++nt)
                acc[mt][nt] = __builtin_amdgcn_mfma_f32_16x16x32_bf16(a[mt], b[nt], acc[mt][nt], 0, 0, 0);
        __syncthreads();
    }

    if (fuse_norm && n0 < 2560) {
        const float* gamma = (n0 < 2048) ? qg : kg;
        float* red = (float*)As;             // 256 floats, As is dead
        // per-row sum of squares: lane partial over its 4 nt cols,
        // shuffle-reduce over l15 (16 lanes = 64 cols of this wave)
#pragma unroll
        for (int mt = 0; mt < 4; ++mt)
#pragma unroll
            for (int r = 0; r < 4; ++r) {
                float p = 0.f;
#pragma unroll
                for (int nt = 0; nt < 4; ++nt) p += acc[mt][nt][r] * acc[mt][nt][r];
#pragma unroll
                for (int msk = 1; msk < 16; msk <<= 1) p += __shfl_xor(p, msk);
                if (l15 == 0)
                    red[(wm * 64 + mt * 16 + quad * 4 + r) * 2 + wn] = p;
            }
        __syncthreads();
        float gv[4];
#pragma unroll
        for (int nt = 0; nt < 4; ++nt) gv[nt] = gamma[wn * 64 + nt * 16 + l15];
#pragma unroll
        for (int mt = 0; mt < 4; ++mt)
#pragma unroll
            for (int r = 0; r < 4; ++r) {
                int rl = wm * 64 + mt * 16 + quad * 4 + r;
                float m2 = red[rl * 2] + red[rl * 2 + 1];
                float sc = rsqrtf(m2 * (1.0f / 128.0f) + 1e-8f);
#pragma unroll
                for (int nt = 0; nt < 4; ++nt) acc[mt][nt][r] *= sc * gv[nt];
            }
    }

#pragma unroll
    for (int mt = 0; mt < 4; ++mt) {
#pragma unroll
        for (int r = 0; r < 4; ++r) {
            int row = m0 + wm * 64 + mt * 16 + quad * 4 + r;
#pragma unroll
            for (int nt = 0; nt < 4; ++nt) {
                int col = n0 + wn * 64 + nt * 16 + l15;
                float v = acc[mt][nt][r];
                if (resid) v += resid[(size_t)row * ldc + col];
                if (c_f32) ((float*)C)[(size_t)row * ldc + col] = v;
                else       ((u16*)C)[(size_t)row * ldc + col] = f2u(v);
            }
        }
    }
}

// ---------------------------------------------------------------------------
// V transpose: vT[(b*4+kvh)*128 + d][s] = qkv[(b*2048+s)][2560 + kvh*128 + d]
// grid (32, 4, 2), block 256.  (bf16)
__global__ __launch_bounds__(256) void vtrans(
    const u16* __restrict__ qkv, u16* __restrict__ vT)
{
    __shared__ u16 T[128 * 72];
    const int tid = threadIdx.x;
    const int t0 = blockIdx.x * 64;
    const int kvh = blockIdx.y, b = blockIdx.z;
#pragma unroll
    for (int i = 0; i < 4; ++i) {
        int c = tid + i * 256;                // 0..1023
        int tl = c >> 4, d8 = (c & 15) * 8;
        short8 v = *(const short8*)&qkv[(size_t)(b * 2048 + t0 + tl) * 3072 + 2560 + kvh * 128 + d8];
#pragma unroll
        for (int j = 0; j < 8; ++j)
            T[(d8 + j) * 72 + tl] = (u16)v[j];
    }
    __syncthreads();
#pragma unroll
    for (int i = 0; i < 4; ++i) {
        int c = tid + i * 256;
        int d = c >> 3, t8 = (c & 7) * 8;
        *(short8*)&vT[((size_t)(b * 4 + kvh) * 128 + d) * 2048 + t0 + t8] =
            *(const short8*)&T[d * 72 + t8];
    }
}

// ---------------------------------------------------------------------------
// Flash attention, causal, GQA, PAIRED q-tiles (qt, 31-qt) => uniform 33
// kv-tiles/block, no CU-stacking imbalance.  Row strides 136/72 u16: both are
// ODD multiples of 16 B -> ds_*_b128 stays legal (round-6 lesson: stride must
// be a multiple of 8 u16 or the compiler splits into 4x b32 = 3x slower).
// grid (16, 16, 2), block 256.  LDS 54,272 B -> 2 blocks/CU (= grid depth).
#define QS 136
#define VS 72
__global__ __launch_bounds__(256) void attn(
    u16* __restrict__ qkv, const u16* __restrict__ vT)
{
    __shared__ u16 lds[27136];               // 54,272 B
    u16* const Ks  = lds;                    // [64][QS]   8704
    u16* const Vs  = lds + 8704;             // [128][VS]  9216
    u16* const Psb[2] = { lds + 17920, lds + 22528 };  // 2x [64][VS] 4608
    // Q staging overlays Vs+Ps (dead until first kv iteration):
    u16* const Qsb[2] = { lds + 8704, lds + 17408 };   // 2x [64][QS]

    const int tid = threadIdx.x, lane = tid & 63, w = tid >> 6;
    const int l15 = lane & 15, quad = lane >> 4;
    const int h = blockIdx.y, b = blockIdx.z;
    const int kvh = h >> 2;
    const int qts[2] = { (int)blockIdx.x, 31 - (int)blockIdx.x };
    const float scale = 0.08838834764831845f;

    // stage both Q tiles, pull fragments to registers
#pragma unroll
    for (int t = 0; t < 2; ++t)
#pragma unroll
        for (int i = 0; i < 4; ++i) {
            int c = tid + i * 256;
            int r = c >> 4, d8 = (c & 15) * 8;
            *(short8*)&Qsb[t][r * QS + d8] =
                *(const short8*)&qkv[(size_t)(b * 2048 + qts[t] * 64 + r) * 3072 + h * 128 + d8];
        }
    __syncthreads();
    short8 qf[2][4];
#pragma unroll
    for (int t = 0; t < 2; ++t)
#pragma unroll
        for (int ks = 0; ks < 4; ++ks)
            qf[t][ks] = *(const short8*)&Qsb[t][(w * 16 + l15) * QS + ks * 32 + quad * 8];
    __syncthreads();   // Q region about to be reused as Vs/Ps

    f32x4 o[2][8] = {};
    float mrow[2][4], lrow[2][4];
#pragma unroll
    for (int t = 0; t < 2; ++t)
#pragma unroll
        for (int r = 0; r < 4; ++r) { mrow[t][r] = -1e30f; lrow[t][r] = 0.f; }

    for (int kt = 0; kt <= qts[1]; ++kt) {
        const int kv0 = kt * 64;
#pragma unroll
        for (int i = 0; i < 4; ++i) {
            int c = tid + i * 256;
            int r = c >> 4, d8 = (c & 15) * 8;
            *(short8*)&Ks[r * QS + d8] =
                *(const short8*)&qkv[(size_t)(b * 2048 + kv0 + r) * 3072 + 2048 + kvh * 128 + d8];
        }
#pragma unroll
        for (int i = 0; i < 4; ++i) {
            int c = tid + i * 256;
            int d = c >> 3, t8 = (c & 7) * 8;
            *(short8*)&Vs[d * VS + t8] =
                *(const short8*)&vT[((size_t)(b * 4 + kvh) * 128 + d) * 2048 + kv0 + t8];
        }
        __syncthreads();

#pragma unroll
        for (int t = 0; t < 2; ++t) {
            if (kt > qts[t]) continue;       // tile done (wave-uniform branch)
            // S = Q K^T  (16 q-rows x 64 kv-cols)
            f32x4 s[4];
#pragma unroll
            for (int nt = 0; nt < 4; ++nt) {
                f32x4 a = {};
#pragma unroll
                for (int ks = 0; ks < 4; ++ks) {
                    short8 bk = *(const short8*)&Ks[(nt * 16 + l15) * QS + ks * 32 + quad * 8];
                    a = __builtin_amdgcn_mfma_f32_16x16x32_bf16(qf[t][ks], bk, a, 0, 0, 0);
                }
                s[nt] = a;
            }
            const bool diag = (kt == qts[t]);
#pragma unroll
            for (int nt = 0; nt < 4; ++nt) {
                int col = nt * 16 + l15;
#pragma unroll
                for (int r = 0; r < 4; ++r) {
                    float v = s[nt][r] * scale;
                    if (diag) {
                        int row = w * 16 + quad * 4 + r;
                        if (col > row) v = -1e30f;
                    }
                    s[nt][r] = v;
                }
            }
            // online softmax
            float alpha[4];
#pragma unroll
            for (int r = 0; r < 4; ++r) {
                float mx = s[0][r];
#pragma unroll
                for (int nt = 1; nt < 4; ++nt) mx = fmaxf(mx, s[nt][r]);
#pragma unroll
                for (int msk = 1; msk < 16; msk <<= 1) mx = fmaxf(mx, __shfl_xor(mx, msk));
                float mn = fmaxf(mrow[t][r], mx);
                alpha[r] = __expf(mrow[t][r] - mn);
                mrow[t][r] = mn;
            }
#pragma unroll
            for (int r = 0; r < 4; ++r) {
                float sum = 0.f;
#pragma unroll
                for (int nt = 0; nt < 4; ++nt) {
                    float p = __expf(s[nt][r] - mrow[t][r]);
                    s[nt][r] = p;
                    sum += p;
                }
#pragma unroll
                for (int msk = 1; msk < 16; msk <<= 1) sum += __shfl_xor(sum, msk);
                lrow[t][r] = lrow[t][r] * alpha[r] + sum;
            }
#pragma unroll
            for (int nt = 0; nt < 4; ++nt)
#pragma unroll
                for (int r = 0; r < 4; ++r)
                    Psb[t][(w * 16 + quad * 4 + r) * VS + nt * 16 + l15] = f2u(s[nt][r]);
#pragma unroll
            for (int nto = 0; nto < 8; ++nto)
#pragma unroll
                for (int r = 0; r < 4; ++r)
                    o[t][nto][r] *= alpha[r];
        }
        __syncthreads();

        // O += P @ V  (per active tile)
#pragma unroll
        for (int t = 0; t < 2; ++t) {
            if (kt > qts[t]) continue;
            short8 pa[2];
#pragma unroll
            for (int ks = 0; ks < 2; ++ks)
                pa[ks] = *(const short8*)&Psb[t][(w * 16 + l15) * VS + ks * 32 + quad * 8];
#pragma unroll
            for (int nto = 0; nto < 8; ++nto) {
#pragma unroll
                for (int ks = 0; ks < 2; ++ks) {
                    short8 bv = *(const short8*)&Vs[(nto * 16 + l15) * VS + ks * 32 + quad * 8];
                    o[t][nto] = __builtin_amdgcn_mfma_f32_16x16x32_bf16(pa[ks], bv, o[t][nto], 0, 0, 0);
                }
            }
        }
        __syncthreads();
    }
    // write O in-place over the Q slice (row stride 3072)
#pragma unroll
    for (int t = 0; t < 2; ++t)
#pragma unroll
        for (int r = 0; r < 4; ++r) {
            float inv = 1.0f / lrow[t][r];
            int row = qts[t] * 64 + w * 16 + quad * 4 + r;
#pragma unroll
            for (int nto = 0; nto < 8; ++nto)
                qkv[(size_t)(b * 2048 + row) * 3072 + h * 128 + nto * 16 + l15] =
                    f2u(o[t][nto][r] * inv);
        }
}

// ---------------------------------------------------------------------------
// Workspace layout (peak 46.1 MiB, proven):
//   [0,         8388608)  WoT   [2048][2048]   live until final GEMM
//   [8388608,  33554432)  QKV   [4096][3072]   q-slice becomes O in-place
//   [33554432, 37748736)  vT    [8][128][2048] written AFTER WTqkv is dead
//   [33554432, 46137344)  WTqkv [3072][2048]   dead after QKV GEMM
// xbf (bf16 copy of x, 16.8 MB) lives in d_out (dead until final GEMM).
extern "C" void kernel_launch(void* const* d_in, const int* in_sizes, int n_in,
                              void* d_out, int out_size, void* d_ws, size_t ws_size,
                              hipStream_t stream) {
    const float* x  = (const float*)d_in[0];   // [2,2048,2048] fp32
    const float* Wq = (const float*)d_in[1];   // [2048,2048]
    const float* Wk = (const float*)d_in[2];   // [2048,512]
    const float* Wv = (const float*)d_in[3];   // [2048,512]
    const float* Wo = (const float*)d_in[4];   // [2048,2048]
    const float* qg = (const float*)d_in[5];   // [128]
    const float* kg = (const float*)d_in[6];   // [128]

    char* ws = (char*)d_ws;
    u16* WoT   = (u16*)(ws);
    u16* QKV   = (u16*)(ws + 8388608);
    u16* vT    = (u16*)(ws + 33554432);
    u16* WTqkv = (u16*)(ws + 33554432);
    u16* xbf   = (u16*)d_out;                  // 16.8 MB of 33.5 MB; dead at GEMM2

    // 0. x -> bf16 (memory-bound)
    cvt_bf16<<<dim3(4096), 256, 0, stream>>>(x, xbf, 8388608);

    // 1. all weight transposes in one launch
    transpose_all<<<dim3(2560), 256, 0, stream>>>(Wq, Wk, Wv, Wo, WTqkv, WoT);

    // 2. QKV projection with FUSED per-head RMSNorm on q/k tiles
    gemm_lds<<<dim3(24, 32), 256, 0, stream>>>(xbf, 2048, WTqkv, QKV, 3072,
                                               nullptr, 0, 4096, 3072, 2048,
                                               qg, kg, 1);

    // 3. V transpose (WTqkv now dead; vT overlays it)
    vtrans<<<dim3(32, 4, 2), 256, 0, stream>>>(QKV, vT);

    // 4. causal GQA flash attention (paired q-tiles), O in-place into QKV
    attn<<<dim3(16, 16, 2), 256, 0, stream>>>(QKV, vT);

    // 5. output projection + residual (C = d_out fp32)
    gemm_lds<<<dim3(16, 32), 256, 0, stream>>>(QKV, 3072, WoT, d_out, 2048,
                                               x, 1, 4096, 2048, 2048,
                                               nullptr, nullptr, 0);
}

// Round 8
// 354.423 us; speedup vs baseline: 1.7563x; 1.0490x over previous
//
#include <hip/hip_runtime.h>

typedef unsigned short u16;
typedef __attribute__((ext_vector_type(8))) short short8;   // 8 x bf16 (4 VGPRs)
typedef __attribute__((ext_vector_type(4))) float f32x4;    // MFMA C/D frag

#define DEVI __device__ __forceinline__

DEVI float u2f(u16 u) {
    unsigned int x = ((unsigned int)u) << 16;
    float f; __builtin_memcpy(&f, &x, 4); return f;
}
DEVI u16 f2u(float f) {  // RNE bf16 (finite values)
    unsigned int x; __builtin_memcpy(&x, &f, 4);
    x = (x + 0x7fffu + ((x >> 16) & 1u)) >> 16;
    return (u16)x;
}
DEVI unsigned int fbits(float f) {
    unsigned int x; __builtin_memcpy(&x, &f, 4); return x;
}
// async global->LDS, 16B per lane; lds base must be wave-uniform (m104/m108)
DEVI void gld16(const u16* g, u16* ldsbase) {
    __builtin_amdgcn_global_load_lds(
        (const __attribute__((address_space(1))) unsigned int*)g,
        (__attribute__((address_space(3))) unsigned int*)ldsbase, 16, 0, 0);
}

// ---------------------------------------------------------------------------
// Prep (one launch): blocks 0..4095 convert x fp32->bf16 (8 floats/thread);
// blocks 4096..6655 transpose the four weight matrices to K-inner bf16.
// grid 6656, block 256.
__global__ __launch_bounds__(256) void prep(
    const float* __restrict__ x,
    const float* __restrict__ Wq, const float* __restrict__ Wk,
    const float* __restrict__ Wv, const float* __restrict__ Wo,
    u16* __restrict__ xbf, u16* __restrict__ WTqkv, u16* __restrict__ WoT)
{
    __shared__ u16 T[64 * 72];
    int id = blockIdx.x;
    const int tid = threadIdx.x;
    if (id < 4096) {
        int g = (id * 256 + tid) * 8;
        float4 a = *(const float4*)&x[g];
        float4 c = *(const float4*)&x[g + 4];
        short8 v;
        v[0]=(short)f2u(a.x); v[1]=(short)f2u(a.y); v[2]=(short)f2u(a.z); v[3]=(short)f2u(a.w);
        v[4]=(short)f2u(c.x); v[5]=(short)f2u(c.y); v[6]=(short)f2u(c.z); v[7]=(short)f2u(c.w);
        *(short8*)&xbf[g] = v;
        return;
    }
    id -= 4096;
    const float* W; u16* WT; int N, bx, by;
    if (id < 1024)      {            W = Wo; WT = WoT;   N = 2048; bx = id & 31; by = id >> 5; }
    else if (id < 2048) { id -= 1024; W = Wq; WT = WTqkv; N = 2048; bx = id & 31; by = id >> 5; }
    else if (id < 2304) { id -= 2048; W = Wk; WT = WTqkv + (size_t)2048 * 2048; N = 512; bx = id & 7; by = id >> 3; }
    else                { id -= 2304; W = Wv; WT = WTqkv + (size_t)2560 * 2048; N = 512; bx = id & 7; by = id >> 3; }
    const int K = 2048;
    const int k0 = by * 64, n0 = bx * 64;
#pragma unroll
    for (int i = 0; i < 2; ++i) {
        int c = tid + i * 256;              // 0..511
        int row = c >> 3, n8 = (c & 7) * 8;
        const float* src = &W[(size_t)(k0 + row) * N + n0 + n8];
#pragma unroll
        for (int j = 0; j < 8; ++j)
            T[(n8 + j) * 72 + row] = f2u(src[j]);
    }
    __syncthreads();
#pragma unroll
    for (int i = 0; i < 2; ++i) {
        int c = tid + i * 256;
        int n = c >> 3, k8 = (c & 7) * 8;
        *(short8*)&WT[(size_t)(n0 + n) * K + k0 + k8] = *(const short8*)&T[n * 72 + k8];
    }
}

// ---------------------------------------------------------------------------
// GEMM: C[M][N] = A[M][K] @ WT[N][K]^T (+ optional fp32 residual).
// m97 structure: unpadded [128][32] LDS tiles, global_load_lds width=16.
// If fuse_norm: N-tiles with n0<2560 get per-head RMSNorm fused in epilogue.
// C written fp32 if c_f32 else bf16.  grid (N/128, M/128), block 256.
__global__ __launch_bounds__(256) void gemm_lds(
    const u16* __restrict__ A, int lda,
    const u16* __restrict__ WT,
    void* __restrict__ C, int ldc, const float* __restrict__ resid, int c_f32,
    int M, int N, int K,
    const float* __restrict__ qg, const float* __restrict__ kg, int fuse_norm)
{
    __shared__ u16 As[128 * 32];
    __shared__ u16 Bs[128 * 32];
    const int tid = threadIdx.x;
    const int lane = tid & 63, w = tid >> 6;
    const int wm = w >> 1, wn = w & 1;
    const int l15 = lane & 15, quad = lane >> 4;
    const int r4 = lane >> 2, c4 = (lane & 3) * 8;  // DMA: lane->row/col-8
    const int m0 = blockIdx.y * 128, n0 = blockIdx.x * 128;

    f32x4 acc[4][4] = {};
    for (int k0 = 0; k0 < K; k0 += 32) {
#pragma unroll
        for (int j = 0; j < 2; ++j) {
            int row = w * 32 + j * 16;
            gld16(&WT[(size_t)(n0 + row + r4) * K + k0 + c4], &Bs[row * 32]);
            gld16(&A [(size_t)(m0 + row + r4) * lda + k0 + c4], &As[row * 32]);
        }
        __syncthreads();
        short8 a[4], b[4];
#pragma unroll
        for (int mt = 0; mt < 4; ++mt)
            a[mt] = *(const short8*)&As[(wm * 64 + mt * 16 + l15) * 32 + quad * 8];
#pragma unroll
        for (int nt = 0; nt < 4; ++nt)
            b[nt] = *(const short8*)&Bs[(wn * 64 + nt * 16 + l15) * 32 + quad * 8];
#pragma unroll
        for (int mt = 0; mt < 4; ++mt)
#pragma unroll
            for (int nt = 0; nt < 4; ++nt)
                acc[mt][nt] = __builtin_amdgcn_mfma_f32_16x16x32_bf16(a[mt], b[nt], acc[mt][nt], 0, 0, 0);
        __syncthreads();
    }

    if (fuse_norm && n0 < 2560) {
        const float* gamma = (n0 < 2048) ? qg : kg;
        float* red = (float*)As;             // 256 floats, As is dead
#pragma unroll
        for (int mt = 0; mt < 4; ++mt)
#pragma unroll
            for (int r = 0; r < 4; ++r) {
                float p = 0.f;
#pragma unroll
                for (int nt = 0; nt < 4; ++nt) p += acc[mt][nt][r] * acc[mt][nt][r];
#pragma unroll
                for (int msk = 1; msk < 16; msk <<= 1) p += __shfl_xor(p, msk);
                if (l15 == 0)
                    red[(wm * 64 + mt * 16 + quad * 4 + r) * 2 + wn] = p;
            }
        __syncthreads();
        float gv[4];
#pragma unroll
        for (int nt = 0; nt < 4; ++nt) gv[nt] = gamma[wn * 64 + nt * 16 + l15];
#pragma unroll
        for (int mt = 0; mt < 4; ++mt)
#pragma unroll
            for (int r = 0; r < 4; ++r) {
                int rl = wm * 64 + mt * 16 + quad * 4 + r;
                float m2 = red[rl * 2] + red[rl * 2 + 1];
                float sc = rsqrtf(m2 * (1.0f / 128.0f) + 1e-8f);
#pragma unroll
                for (int nt = 0; nt < 4; ++nt) acc[mt][nt][r] *= sc * gv[nt];
            }
    }

#pragma unroll
    for (int mt = 0; mt < 4; ++mt) {
#pragma unroll
        for (int r = 0; r < 4; ++r) {
            int row = m0 + wm * 64 + mt * 16 + quad * 4 + r;
#pragma unroll
            for (int nt = 0; nt < 4; ++nt) {
                int col = n0 + wn * 64 + nt * 16 + l15;
                float v = acc[mt][nt][r];
                if (resid) v += resid[(size_t)row * ldc + col];
                if (c_f32) ((float*)C)[(size_t)row * ldc + col] = v;
                else       ((u16*)C)[(size_t)row * ldc + col] = f2u(v);
            }
        }
    }
}

// ---------------------------------------------------------------------------
// V transpose: vT[(b*4+kvh)*128 + d][s] = qkv[(b*2048+s)][2560 + kvh*128 + d]
// grid (32, 4, 2), block 256.  (bf16)
__global__ __launch_bounds__(256) void vtrans(
    const u16* __restrict__ qkv, u16* __restrict__ vT)
{
    __shared__ u16 T[128 * 72];
    const int tid = threadIdx.x;
    const int t0 = blockIdx.x * 64;
    const int kvh = blockIdx.y, b = blockIdx.z;
#pragma unroll
    for (int i = 0; i < 4; ++i) {
        int c = tid + i * 256;                // 0..1023
        int tl = c >> 4, d8 = (c & 15) * 8;
        short8 v = *(const short8*)&qkv[(size_t)(b * 2048 + t0 + tl) * 3072 + 2560 + kvh * 128 + d8];
#pragma unroll
        for (int j = 0; j < 8; ++j)
            T[(d8 + j) * 72 + tl] = (u16)v[j];
    }
    __syncthreads();
#pragma unroll
    for (int i = 0; i < 4; ++i) {
        int c = tid + i * 256;
        int d = c >> 3, t8 = (c & 7) * 8;
        *(short8*)&vT[((size_t)(b * 4 + kvh) * 128 + d) * 2048 + t0 + t8] =
            *(const short8*)&T[d * 72 + t8];
    }
}

// ---------------------------------------------------------------------------
// Flash attention, causal, GQA, paired q-tiles (qt, 31-qt) => uniform 33
// kv-tiles/block.  S computed TRANSPOSED (mfma(K,Q) => kv=row, q=col) so the
// P matrix never touches LDS: softmax state is one scalar/lane (q=l15),
// reduction = 15 in-lane ops + 2 cross-quad shuffles, and the PV A-fragment
// is built in-register via v_perm bf16 packs + lane shuffles.
// 2 barriers/kv-iter (was 3), no Ps buffer (LDS 35.8 KB), no P f2u/ds_write.
// grid (16, 16, 2), block 256.
#define QS 136
#define VS 72
__global__ __launch_bounds__(256) void attn(
    u16* __restrict__ qkv, const u16* __restrict__ vT)
{
    __shared__ u16 lds[17920];               // 35,840 B
    u16* const Ks = lds;                     // [64][QS]   8704
    u16* const Vs = lds + 8704;              // [128][VS]  9216
    // Q staging reuses the whole region: Qsb[t] = lds + t*8704

    const int tid = threadIdx.x, lane = tid & 63, w = tid >> 6;
    const int l15 = lane & 15, quad = lane >> 4;
    const int h = blockIdx.y, b = blockIdx.z;
    const int kvh = h >> 2;
    const int qts[2] = { (int)blockIdx.x, 31 - (int)blockIdx.x };
    const float scale = 0.08838834764831845f;

    // stage both Q tiles, pull fragments to registers
#pragma unroll
    for (int t = 0; t < 2; ++t)
#pragma unroll
        for (int i = 0; i < 4; ++i) {
            int c = tid + i * 256;
            int r = c >> 4, d8 = (c & 15) * 8;
            *(short8*)&lds[t * 8704 + r * QS + d8] =
                *(const short8*)&qkv[(size_t)(b * 2048 + qts[t] * 64 + r) * 3072 + h * 128 + d8];
        }
    __syncthreads();
    short8 qf[2][4];
#pragma unroll
    for (int t = 0; t < 2; ++t)
#pragma unroll
        for (int ks = 0; ks < 4; ++ks)
            qf[t][ks] = *(const short8*)&lds[t * 8704 + (w * 16 + l15) * QS + ks * 32 + quad * 8];
    __syncthreads();   // region about to be reused as Ks/Vs

    f32x4 o[2][8] = {};
    float m_[2] = { -1e30f, -1e30f }, l_[2] = { 0.f, 0.f };

    for (int kt = 0; kt <= qts[1]; ++kt) {
        const int kv0 = kt * 64;
#pragma unroll
        for (int i = 0; i < 4; ++i) {
            int c = tid + i * 256;
            int r = c >> 4, d8 = (c & 15) * 8;
            *(short8*)&Ks[r * QS + d8] =
                *(const short8*)&qkv[(size_t)(b * 2048 + kv0 + r) * 3072 + 2048 + kvh * 128 + d8];
        }
#pragma unroll
        for (int i = 0; i < 4; ++i) {
            int c = tid + i * 256;
            int d = c >> 3, t8 = (c & 7) * 8;
            *(short8*)&Vs[d * VS + t8] =
                *(const short8*)&vT[((size_t)(b * 4 + kvh) * 128 + d) * 2048 + kv0 + t8];
        }
        __syncthreads();

#pragma unroll
        for (int t = 0; t < 2; ++t) {
            if (kt > qts[t]) continue;       // tile done (block-uniform branch)
            // S^T = K Q^T : rows = kv (quad*4+r within 16-tile), cols = q (l15)
            f32x4 s[4];
#pragma unroll
            for (int nt = 0; nt < 4; ++nt) {
                f32x4 a = {};
#pragma unroll
                for (int ks = 0; ks < 4; ++ks) {
                    short8 kf = *(const short8*)&Ks[(nt * 16 + l15) * QS + ks * 32 + quad * 8];
                    a = __builtin_amdgcn_mfma_f32_16x16x32_bf16(kf, qf[t][ks], a, 0, 0, 0);
                }
                s[nt] = a;
            }
            // scale + causal mask (diag tile only); local: kv vs q = w*16+l15
            if (kt == qts[t]) {
                int qrow = w * 16 + l15;
#pragma unroll
                for (int nt = 0; nt < 4; ++nt)
#pragma unroll
                    for (int r = 0; r < 4; ++r) {
                        float v = s[nt][r] * scale;
                        if (nt * 16 + quad * 4 + r > qrow) v = -1e30f;
                        s[nt][r] = v;
                    }
            } else {
#pragma unroll
                for (int nt = 0; nt < 4; ++nt)
#pragma unroll
                    for (int r = 0; r < 4; ++r) s[nt][r] *= scale;
            }
            // online softmax, one q-row per lane (q = l15)
            float mx = s[0][0];
#pragma unroll
            for (int nt = 0; nt < 4; ++nt)
#pragma unroll
                for (int r = 0; r < 4; ++r) mx = fmaxf(mx, s[nt][r]);
            mx = fmaxf(mx, __shfl_xor(mx, 16));
            mx = fmaxf(mx, __shfl_xor(mx, 32));
            float mn = fmaxf(m_[t], mx);
            float alpha = __expf(m_[t] - mn);
            m_[t] = mn;
            float sum = 0.f;
#pragma unroll
            for (int nt = 0; nt < 4; ++nt)
#pragma unroll
                for (int r = 0; r < 4; ++r) {
                    float p = __expf(s[nt][r] - mn);
                    s[nt][r] = p;
                    sum += p;
                }
            sum += __shfl_xor(sum, 16);
            sum += __shfl_xor(sum, 32);
            l_[t] = l_[t] * alpha + sum;
            // pack P pairs to bf16 (truncate): pk[nt][i] = [p[2i] | p[2i+1]<<16]
            unsigned int pk[4][2];
#pragma unroll
            for (int nt = 0; nt < 4; ++nt)
#pragma unroll
                for (int i = 0; i < 2; ++i)
                    pk[nt][i] = __builtin_amdgcn_perm(
                        fbits(s[nt][2 * i + 1]), fbits(s[nt][2 * i]), 0x07060302u);
            // build PV A-frags: lane(l15,quad) chunk c needs kv = 32c+quad*8+j
            int af[2][4];
#pragma unroll
            for (int c = 0; c < 2; ++c)
#pragma unroll
                for (int d = 0; d < 4; ++d) {
                    int src = l15 + 16 * ((quad & 1) * 2 + (d >> 1));
                    int v0 = __shfl((int)pk[2 * c][d & 1], src);
                    int v1 = __shfl((int)pk[2 * c + 1][d & 1], src);
                    af[c][d] = (quad >= 2) ? v1 : v0;
                }
            union { int i4[4]; short8 s8; } ua0, ua1;
#pragma unroll
            for (int d = 0; d < 4; ++d) { ua0.i4[d] = af[0][d]; ua1.i4[d] = af[1][d]; }
            // rescale O rows (q = quad*4+r) by alpha broadcast from lane q
#pragma unroll
            for (int r = 0; r < 4; ++r) {
                float ao = __shfl(alpha, quad * 4 + r);
#pragma unroll
                for (int nto = 0; nto < 8; ++nto) o[t][nto][r] *= ao;
            }
            // O += P V
#pragma unroll
            for (int nto = 0; nto < 8; ++nto) {
                short8 bv0 = *(const short8*)&Vs[(nto * 16 + l15) * VS + quad * 8];
                short8 bv1 = *(const short8*)&Vs[(nto * 16 + l15) * VS + 32 + quad * 8];
                o[t][nto] = __builtin_amdgcn_mfma_f32_16x16x32_bf16(ua0.s8, bv0, o[t][nto], 0, 0, 0);
                o[t][nto] = __builtin_amdgcn_mfma_f32_16x16x32_bf16(ua1.s8, bv1, o[t][nto], 0, 0, 0);
            }
        }
        __syncthreads();   // before restaging Ks/Vs
    }
    // write O in-place over the Q slice (row stride 3072)
#pragma unroll
    for (int t = 0; t < 2; ++t) {
        float rl = 1.0f / l_[t];
#pragma unroll
        for (int r = 0; r < 4; ++r) {
            float inv = __shfl(rl, quad * 4 + r);
            int row = qts[t] * 64 + w * 16 + quad * 4 + r;
#pragma unroll
            for (int nto = 0; nto < 8; ++nto)
                qkv[(size_t)(b * 2048 + row) * 3072 + h * 128 + nto * 16 + l15] =
                    f2u(o[t][nto][r] * inv);
        }
    }
}

// ---------------------------------------------------------------------------
// Workspace layout (peak 46.1 MiB, proven):
//   [0,         8388608)  WoT   [2048][2048]   live until final GEMM
//   [8388608,  33554432)  QKV   [4096][3072]   q-slice becomes O in-place
//   [33554432, 37748736)  vT    [8][128][2048] written AFTER WTqkv is dead
//   [33554432, 46137344)  WTqkv [3072][2048]   dead after QKV GEMM
// xbf (bf16 copy of x, 16.8 MB) lives in d_out (dead until final GEMM).
extern "C" void kernel_launch(void* const* d_in, const int* in_sizes, int n_in,
                              void* d_out, int out_size, void* d_ws, size_t ws_size,
                              hipStream_t stream) {
    const float* x  = (const float*)d_in[0];   // [2,2048,2048] fp32
    const float* Wq = (const float*)d_in[1];   // [2048,2048]
    const float* Wk = (const float*)d_in[2];   // [2048,512]
    const float* Wv = (const float*)d_in[3];   // [2048,512]
    const float* Wo = (const float*)d_in[4];   // [2048,2048]
    const float* qg = (const float*)d_in[5];   // [128]
    const float* kg = (const float*)d_in[6];   // [128]

    char* ws = (char*)d_ws;
    u16* WoT   = (u16*)(ws);
    u16* QKV   = (u16*)(ws + 8388608);
    u16* vT    = (u16*)(ws + 33554432);
    u16* WTqkv = (u16*)(ws + 33554432);
    u16* xbf   = (u16*)d_out;                  // 16.8 MB of 33.5 MB; dead at GEMM2

    // 0. x->bf16 + all weight transposes, one launch
    prep<<<dim3(6656), 256, 0, stream>>>(x, Wq, Wk, Wv, Wo, xbf, WTqkv, WoT);

    // 1. QKV projection with fused per-head RMSNorm on q/k tiles
    gemm_lds<<<dim3(24, 32), 256, 0, stream>>>(xbf, 2048, WTqkv, QKV, 3072,
                                               nullptr, 0, 4096, 3072, 2048,
                                               qg, kg, 1);

    // 2. V transpose (WTqkv now dead; vT overlays it)
    vtrans<<<dim3(32, 4, 2), 256, 0, stream>>>(QKV, vT);

    // 3. causal GQA flash attention (paired q-tiles, register-resident P)
    attn<<<dim3(16, 16, 2), 256, 0, stream>>>(QKV, vT);

    // 4. output projection + residual (C = d_out fp32)
    gemm_lds<<<dim3(16, 32), 256, 0, stream>>>(QKV, 3072, WoT, d_out, 2048,
                                               x, 1, 4096, 2048, 2048,
                                               nullptr, nullptr, 0);
}